// Round 15
// baseline (78.691 us; speedup 1.0000x reference)
//
#include <hip/hip_runtime.h>
#include <stdint.h>
#include <math.h>

// Multiresolution hash encoding, 16 levels.
// grids = {4,5,6,9,12,15,21,27,36,48,63,84,111,147,194,255}
// kh = 256//grid, P = floor(256/kh).
// memset: mws = 0 (maxima workspace; image in [0,1) => max >= 0).
// K1 fused (independent block ranges, co-scheduled):
//   [0,512)      pool levels 0..9 only (8-row bands, LDS stage, atomicMax)
//   [512,1536)   levels 13..15 direct (kh=1, identity bilinear)
//   [1536,2304)  levels 10..12 tiles with SELF-POOLING (kh<=4: window read
//                straight from image, bit-identical max; no mws dependency)
// K2: LDS-tiled bilinear levels 0..9 (hash+gather fused), 16 px/thread.

#define NLVL 16
#define NB   16

__constant__ int   c_P[NLVL]   = {4,5,6,9,12,15,21,28,36,51,64,85,128,256,256,256};
__constant__ int   c_KH[NLVL]  = {64,51,42,28,21,17,12,9,7,5,4,3,2,1,1,1};
__constant__ float c_G[NLVL]   = {4.f,5.f,6.f,9.f,12.f,15.f,21.f,27.f,36.f,48.f,63.f,84.f,111.f,147.f,194.f,255.f};
__constant__ int   c_CUM[14]   = {0,16,41,77,158,302,527,968,1752,3048,5649,9745,16970,33354};

#define CELLS_PB   33354                 // cells/batch layout (unchanged)
#define CELLS_TOT  (CELLS_PB*NB)         // 533664
#define MWS_FLOATS (CELLS_TOT*3)
#define POOL_BLOCKS (NB*32)              // 512
#define DIR_BLOCKS  1024
#define T12_BLOCKS  (3*16*16)            // 768: levels 10..12 tiles
#define K1_BLOCKS   (POOL_BLOCKS + DIR_BLOCKS + T12_BLOCKS)   // 2304
#define TILE_BLOCKS (10*16*16)           // 2560: levels 0..9 tiles

__device__ __forceinline__ uint32_t hash3(float m0, float m1, float m2, float g) {
    uint32_t v0 = (uint32_t)(int)(m0 * g);
    uint32_t v1 = (uint32_t)(int)(m1 * g);
    uint32_t v2 = (uint32_t)(int)(m2 * g);
    return (v0 ^ (v1 * 2654435761u) ^ (v2 * 805459861u)) & 0xFFFFu;
}

// shared tile-render body: given staged s[] (float4 features per window cell),
// window origin (r_lo,c_lo), span_x, plane coords -> write 64x64 output tile
__device__ __forceinline__ void tile_body(const float4* s, int r_lo, int c_lo,
                                          int span_x, int P, int lvl, int b,
                                          int yt0, int xt0, float* __restrict__ out)
{
    int lane = threadIdx.x & 63;
    int w    = threadIdx.x >> 6;
    int xq   = lane & 15;
    int rg   = lane >> 4;
    int xb   = xt0 + xq * 4;

    int ix0t[4], ix1t[4]; float wx1t[4];
#pragma unroll
    for (int j = 0; j < 4; ++j) {
        int numx = (2 * (xb + j) + 1) * P - 256;
        int ix0  = numx >> 9;
        float fx = (float)(numx & 511) * (1.0f / 512.0f);
        int ix1;
        if (ix0 < 0)           { ix0 = 0;     ix1 = 0;     fx = 0.f; }
        else if (ix0 >= P - 1) { ix0 = P - 1; ix1 = P - 1; fx = 0.f; }
        else                   { ix1 = ix0 + 1; }
        ix0t[j] = ix0 - c_lo; ix1t[j] = ix1 - c_lo; wx1t[j] = fx;
    }

#pragma unroll
    for (int k = 0; k < 4; ++k) {
        int y = yt0 + w * 16 + rg * 4 + k;
        int numy = (2 * y + 1) * P - 256;
        int iy0  = numy >> 9;
        float fy = (float)(numy & 511) * (1.0f / 512.0f);
        int iy1;
        if (iy0 < 0)           { iy0 = 0;     iy1 = 0;     fy = 0.f; }
        else if (iy0 >= P - 1) { iy0 = P - 1; iy1 = P - 1; fy = 0.f; }
        else                   { iy1 = iy0 + 1; }
        const float4* p0 = s + (iy0 - r_lo) * span_x;
        const float4* p1 = s + (iy1 - r_lo) * span_x;
        float wy1 = fy, wy0 = 1.f - fy;

        float v[3][4];
#pragma unroll
        for (int j = 0; j < 4; ++j) {
            float wx1 = wx1t[j], wx0 = 1.f - wx1;
            float4 t00 = p0[ix0t[j]];
            float4 t01 = p0[ix1t[j]];
            float4 t10 = p1[ix0t[j]];
            float4 t11 = p1[ix1t[j]];
            v[0][j] = wy0 * (wx0 * t00.x + wx1 * t01.x) + wy1 * (wx0 * t10.x + wx1 * t11.x);
            v[1][j] = wy0 * (wx0 * t00.y + wx1 * t01.y) + wy1 * (wx0 * t10.y + wx1 * t11.y);
            v[2][j] = wy0 * (wx0 * t00.z + wx1 * t01.z) + wy1 * (wx0 * t10.z + wx1 * t11.z);
        }
        float* o = out + ((size_t)b * 48 + 3 * lvl) * 65536 + (size_t)y * 256 + xb;
#pragma unroll
        for (int c = 0; c < 3; ++c) {
            float4 q; q.x = v[c][0]; q.y = v[c][1]; q.z = v[c][2]; q.w = v[c][3];
            *(float4*)(o + (size_t)c * 65536) = q;
        }
    }
}

// window bounds helper
__device__ __forceinline__ void tile_window(int P, int yt0, int xt0,
                                            int& r_lo, int& c_lo, int& span_y, int& span_x)
{
    int nlo  = ((2 * yt0 + 1) * P - 256) >> 9;
    r_lo = nlo < 0 ? 0 : (nlo > P - 1 ? P - 1 : nlo);
    int nhi  = (((2 * (yt0 + 63) + 1) * P - 256) >> 9) + 1;
    int r_hi = nhi < 0 ? 0 : (nhi > P - 1 ? P - 1 : nhi);
    int mlo  = ((2 * xt0 + 1) * P - 256) >> 9;
    c_lo = mlo < 0 ? 0 : (mlo > P - 1 ? P - 1 : mlo);
    int mhi  = (((2 * (xt0 + 63) + 1) * P - 256) >> 9) + 1;
    int c_hi = mhi < 0 ? 0 : (mhi > P - 1 ? P - 1 : mhi);
    span_y = r_hi - r_lo + 1;
    span_x = c_hi - c_lo + 1;
}

// ---- K1: pool(lvl 0..9) + direct(13..15) + self-pooled tiles(10..12) ----
__global__ __launch_bounds__(256) void k1_fused(const float* __restrict__ img,
                                                const float* __restrict__ tab,
                                                unsigned int* __restrict__ mws,
                                                float* __restrict__ out)
{
    static constexpr int K_P[10]   = {4,5,6,9,12,15,21,28,36,51};
    static constexpr int K_KH[10]  = {64,51,42,28,21,17,12,9,7,5};
    static constexpr int K_CUM[10] = {0,16,41,77,158,302,527,968,1752,3048};

    __shared__ float4 sbuf[34 * 34];     // union-style: tiles use sbuf; pool uses simg/colbuf
    __shared__ float simg[3][8][256];
    __shared__ float colbuf[3][256];

    if (blockIdx.x >= POOL_BLOCKS + DIR_BLOCKS) {
        // ---- levels 10..12 tiles, self-pooled from image ----
        int blk2  = blockIdx.x - (POOL_BLOCKS + DIR_BLOCKS);   // 0..767
        int lvl   = 10 + (blk2 >> 8);
        int rem   = blk2 & 255;
        int b     = rem >> 4;
        int tile  = rem & 15;
        int P     = c_P[lvl], kh = c_KH[lvl];
        int yt0   = (tile >> 2) * 64;
        int xt0   = (tile & 3) * 64;

        int r_lo, c_lo, span_y, span_x;
        tile_window(P, yt0, xt0, r_lo, c_lo, span_y, span_x);

        const float* T = tab + (size_t)lvl * 196608;
        const float* ib = img + (size_t)b * 196608;
        float gmul = c_G[lvl];
        int n = span_y * span_x;
        for (int t = threadIdx.x; t < n; t += 256) {
            int r = t / span_x, c = t - r * span_x;
            const float* ip = ib + (size_t)(r_lo + r) * kh * 256 + (c_lo + c) * kh;
            float m0 = -INFINITY, m1 = -INFINITY, m2 = -INFINITY;
            for (int rr = 0; rr < kh; ++rr)
                for (int cc = 0; cc < kh; ++cc) {
                    int o = rr * 256 + cc;
                    m0 = fmaxf(m0, ip[o]);
                    m1 = fmaxf(m1, ip[65536 + o]);
                    m2 = fmaxf(m2, ip[131072 + o]);
                }
            uint32_t g = hash3(m0, m1, m2, gmul);
            float3 tv = *(const float3*)(T + g * 3);
            float4 fv; fv.x = tv.x; fv.y = tv.y; fv.z = tv.z; fv.w = 0.f;
            sbuf[t] = fv;
        }
        __syncthreads();
        tile_body(sbuf, r_lo, c_lo, span_x, P, lvl, b, yt0, xt0, out);
        return;
    }

    if (blockIdx.x >= POOL_BLOCKS) {
        // ---- direct path, levels 13..15 ----
        int t = (blockIdx.x - POOL_BLOCKS) * 256 + threadIdx.x;   // 262144 total
        int b = t >> 14;
        int pix0 = (t & 16383) << 2;
        const float* p = img + (size_t)b * 196608 + pix0;
        float4 i0 = *(const float4*)p;
        float4 i1 = *(const float4*)(p + 65536);
        float4 i2 = *(const float4*)(p + 131072);
#pragma unroll
        for (int lvl = 13; lvl < 16; ++lvl) {
            float g = c_G[lvl];
            const float* T = tab + (size_t)lvl * 196608;
            uint32_t g0 = hash3(i0.x, i1.x, i2.x, g);
            uint32_t g1 = hash3(i0.y, i1.y, i2.y, g);
            uint32_t g2 = hash3(i0.z, i1.z, i2.z, g);
            uint32_t g3 = hash3(i0.w, i1.w, i2.w, g);
            float3 f0 = *(const float3*)(T + g0 * 3);
            float3 f1 = *(const float3*)(T + g1 * 3);
            float3 f2 = *(const float3*)(T + g2 * 3);
            float3 f3 = *(const float3*)(T + g3 * 3);
            float4 o0, o1, o2;
            o0.x = f0.x; o1.x = f0.y; o2.x = f0.z;
            o0.y = f1.x; o1.y = f1.y; o2.y = f1.z;
            o0.z = f2.x; o1.z = f2.y; o2.z = f2.z;
            o0.w = f3.x; o1.w = f3.y; o2.w = f3.z;
            float* ob = out + ((size_t)b * 48 + 3 * lvl) * 65536 + pix0;
            *(float4*)ob            = o0;
            *(float4*)(ob + 65536)  = o1;
            *(float4*)(ob + 131072) = o2;
        }
        return;
    }

    // ---- pool path: 8-row band, levels 0..9 only ----
    int b    = blockIdx.x >> 5;
    int band = blockIdx.x & 31;
    int y0   = band * 8;

    const float* base = img + (size_t)b * 196608 + (size_t)y0 * 256;
    for (int t = threadIdx.x; t < 1536; t += 256) {
        int ch = t >> 9;
        int r  = t & 511;
        float4 v = *(const float4*)(base + (size_t)ch * 65536 + r * 4);
        int row = r >> 6, c4 = (r & 63) << 2;
        simg[ch][row][c4 + 0] = v.x;
        simg[ch][row][c4 + 1] = v.y;
        simg[ch][row][c4 + 2] = v.z;
        simg[ch][row][c4 + 3] = v.w;
    }
    __syncthreads();

    int x = threadIdx.x;
#pragma unroll
    for (int lvl = 0; lvl < 10; ++lvl) {
        const int kh = K_KH[lvl], P = K_P[lvl];
        int nr0 = y0 / kh;
        int nr1 = (y0 + 7) / kh; if (nr1 > P - 1) nr1 = P - 1;
        for (int cr = nr0; cr <= nr1; ++cr) {
            int rlo = cr * kh;      if (rlo < y0) rlo = y0;
            int rhi = cr * kh + kh; if (rhi > y0 + 8) rhi = y0 + 8;
            float p0 = -INFINITY, p1 = -INFINITY, p2 = -INFINITY;
            for (int r = rlo; r < rhi; ++r) {
                int rr = r - y0;
                p0 = fmaxf(p0, simg[0][rr][x]);
                p1 = fmaxf(p1, simg[1][rr][x]);
                p2 = fmaxf(p2, simg[2][rr][x]);
            }
            colbuf[0][x] = p0; colbuf[1][x] = p1; colbuf[2][x] = p2;
            __syncthreads();
            if (x < P) {
                float q0 = -INFINITY, q1 = -INFINITY, q2 = -INFINITY;
                for (int c = x * kh; c < x * kh + kh; ++c) {
                    q0 = fmaxf(q0, colbuf[0][c]);
                    q1 = fmaxf(q1, colbuf[1][c]);
                    q2 = fmaxf(q2, colbuf[2][c]);
                }
                int idx = K_CUM[lvl] * NB + b * P * P + cr * P + x;
                atomicMax(&mws[idx],                 __float_as_uint(q0));
                atomicMax(&mws[idx + CELLS_TOT],     __float_as_uint(q1));
                atomicMax(&mws[idx + 2 * CELLS_TOT], __float_as_uint(q2));
            }
            __syncthreads();
        }
    }
}

// ---- K2: LDS-tiled bilinear levels 0..9 (hash+gather fused) ----
__global__ __launch_bounds__(256) void render_tiles(const float* __restrict__ tab,
                                                    const float* __restrict__ mws,
                                                    float* __restrict__ out)
{
    __shared__ float4 s[34 * 34];
    int blk   = blockIdx.x;
    int tile  = blk & 15;
    int plane = blk >> 4;            // 0..159
    int lvl   = plane >> 4;
    int b     = plane & 15;
    int P     = c_P[lvl];
    int yt0   = (tile >> 2) * 64;
    int xt0   = (tile & 3) * 64;

    int r_lo, c_lo, span_y, span_x;
    tile_window(P, yt0, xt0, r_lo, c_lo, span_y, span_x);

    int planebase = c_CUM[lvl] * NB + b * P * P;
    const float* T = tab + (size_t)lvl * 196608;
    float gmul = c_G[lvl];
    int n = span_y * span_x;
    for (int t = threadIdx.x; t < n; t += 256) {
        int r = t / span_x, c = t - r * span_x;
        int idx = planebase + (r_lo + r) * P + c_lo + c;
        float m0 = mws[idx];
        float m1 = mws[idx + CELLS_TOT];
        float m2 = mws[idx + 2 * CELLS_TOT];
        uint32_t g = hash3(m0, m1, m2, gmul);
        float3 tv = *(const float3*)(T + g * 3);
        float4 fv; fv.x = tv.x; fv.y = tv.y; fv.z = tv.z; fv.w = 0.f;
        s[t] = fv;
    }
    __syncthreads();
    tile_body(s, r_lo, c_lo, span_x, P, lvl, b, yt0, xt0, out);
}

extern "C" void kernel_launch(void* const* d_in, const int* in_sizes, int n_in,
                              void* d_out, int out_size, void* d_ws, size_t ws_size,
                              hipStream_t stream)
{
    const float* img = (const float*)d_in[0];   // (16,3,256,256) f32
    const float* tab = (const float*)d_in[1];   // (16,65536,3) f32
    float* out = (float*)d_out;                 // (16,48,256,256) f32
    float* mws = (float*)d_ws;                  // 6.4 MB (levels 0..9 used)

    (void)hipMemsetAsync(mws, 0, (size_t)MWS_FLOATS * sizeof(float), stream);
    hipLaunchKernelGGL(k1_fused,     dim3(K1_BLOCKS), dim3(256), 0, stream, img, tab, (unsigned int*)mws, out);
    hipLaunchKernelGGL(render_tiles, dim3(TILE_BLOCKS), dim3(256), 0, stream, tab, mws, out);
}

// Round 16
// 74.972 us; speedup vs baseline: 1.0496x; 1.0496x over previous
//
#include <hip/hip_runtime.h>
#include <stdint.h>
#include <math.h>

// Multiresolution hash encoding, 16 levels.
// grids = {4,5,6,9,12,15,21,27,36,48,63,84,111,147,194,255}
// kh = 256//grid, P = floor(256/kh).
// memset: mws = 0 (maxima workspace; image in [0,1) => max >= 0).
// K1 fused: blocks [0,512)    = pooling levels 0..12 (8-row bands, atomicMax)
//           blocks [512,1536) = levels 13..15 direct (kh=1, identity bilinear)
// K2: LDS-tiled bilinear levels 0..12 (hash+gather fused into staging),
//     16 px/thread, float4 stores, cached x-interpolated row pair.

#define NLVL 16
#define NB   16

__constant__ int   c_P[NLVL]   = {4,5,6,9,12,15,21,28,36,51,64,85,128,256,256,256};
__constant__ float c_G[NLVL]   = {4.f,5.f,6.f,9.f,12.f,15.f,21.f,27.f,36.f,48.f,63.f,84.f,111.f,147.f,194.f,255.f};
__constant__ int   c_CUM[14]   = {0,16,41,77,158,302,527,968,1752,3048,5649,9745,16970,33354};

#define CELLS_PB   33354                 // cells/batch, levels 0..12
#define CELLS_TOT  (CELLS_PB*NB)         // 533664
#define MWS_FLOATS (CELLS_TOT*3)         // 1600992
#define POOL_BLOCKS (NB*32)              // 512: (batch, 8-row band)
#define DIR_BLOCKS  1024
#define K1_BLOCKS   (POOL_BLOCKS + DIR_BLOCKS)   // 1536
#define TILE_BLOCKS (13*16*16)           // 3328

__device__ __forceinline__ uint32_t hash3(float m0, float m1, float m2, float g) {
    uint32_t v0 = (uint32_t)(int)(m0 * g);
    uint32_t v1 = (uint32_t)(int)(m1 * g);
    uint32_t v2 = (uint32_t)(int)(m2 * g);
    return (v0 ^ (v1 * 2654435761u) ^ (v2 * 805459861u)) & 0xFFFFu;
}

// ---- K1: fused pooling (8-row bands, levels 0..12) + direct levels 13..15 ----
__global__ __launch_bounds__(256) void pool_direct(const float* __restrict__ img,
                                                   const float* __restrict__ tab,
                                                   unsigned int* __restrict__ mws,
                                                   float* __restrict__ out)
{
    static constexpr int K_P[13]   = {4,5,6,9,12,15,21,28,36,51,64,85,128};
    static constexpr int K_KH[13]  = {64,51,42,28,21,17,12,9,7,5,4,3,2};
    static constexpr int K_CUM[13] = {0,16,41,77,158,302,527,968,1752,3048,5649,9745,16970};

    __shared__ float simg[3][8][256];
    __shared__ float colbuf[3][256];

    if (blockIdx.x >= POOL_BLOCKS) {
        // direct path, levels 13..15: identity bilinear, 4 px/thread
        int t = (blockIdx.x - POOL_BLOCKS) * 256 + threadIdx.x;   // 262144 total
        int b = t >> 14;
        int pix0 = (t & 16383) << 2;
        const float* p = img + (size_t)b * 196608 + pix0;
        float4 i0 = *(const float4*)p;
        float4 i1 = *(const float4*)(p + 65536);
        float4 i2 = *(const float4*)(p + 131072);
#pragma unroll
        for (int lvl = 13; lvl < 16; ++lvl) {
            float g = c_G[lvl];
            const float* T = tab + (size_t)lvl * 196608;
            uint32_t g0 = hash3(i0.x, i1.x, i2.x, g);
            uint32_t g1 = hash3(i0.y, i1.y, i2.y, g);
            uint32_t g2 = hash3(i0.z, i1.z, i2.z, g);
            uint32_t g3 = hash3(i0.w, i1.w, i2.w, g);
            float3 f0 = *(const float3*)(T + g0 * 3);
            float3 f1 = *(const float3*)(T + g1 * 3);
            float3 f2 = *(const float3*)(T + g2 * 3);
            float3 f3 = *(const float3*)(T + g3 * 3);
            float4 o0, o1, o2;
            o0.x = f0.x; o1.x = f0.y; o2.x = f0.z;
            o0.y = f1.x; o1.y = f1.y; o2.y = f1.z;
            o0.z = f2.x; o1.z = f2.y; o2.z = f2.z;
            o0.w = f3.x; o1.w = f3.y; o2.w = f3.z;
            float* ob = out + ((size_t)b * 48 + 3 * lvl) * 65536 + pix0;
            *(float4*)ob            = o0;
            *(float4*)(ob + 65536)  = o1;
            *(float4*)(ob + 131072) = o2;
        }
        return;
    }

    // pool path: 8-row band
    int b    = blockIdx.x >> 5;
    int band = blockIdx.x & 31;
    int y0   = band * 8;

    const float* base = img + (size_t)b * 196608 + (size_t)y0 * 256;
    for (int t = threadIdx.x; t < 1536; t += 256) {      // 1536 float4 = 3ch x 8rows x 256
        int ch = t >> 9;
        int r  = t & 511;
        float4 v = *(const float4*)(base + (size_t)ch * 65536 + r * 4);
        int row = r >> 6, c4 = (r & 63) << 2;
        simg[ch][row][c4 + 0] = v.x;
        simg[ch][row][c4 + 1] = v.y;
        simg[ch][row][c4 + 2] = v.z;
        simg[ch][row][c4 + 3] = v.w;
    }
    __syncthreads();

    int x = threadIdx.x;
#pragma unroll
    for (int lvl = 0; lvl < 13; ++lvl) {
        const int kh = K_KH[lvl], P = K_P[lvl];
        int nr0 = y0 / kh;
        int nr1 = (y0 + 7) / kh; if (nr1 > P - 1) nr1 = P - 1;
        for (int cr = nr0; cr <= nr1; ++cr) {
            int rlo = cr * kh;      if (rlo < y0) rlo = y0;
            int rhi = cr * kh + kh; if (rhi > y0 + 8) rhi = y0 + 8;
            float p0 = -INFINITY, p1 = -INFINITY, p2 = -INFINITY;
            for (int r = rlo; r < rhi; ++r) {
                int rr = r - y0;
                p0 = fmaxf(p0, simg[0][rr][x]);
                p1 = fmaxf(p1, simg[1][rr][x]);
                p2 = fmaxf(p2, simg[2][rr][x]);
            }
            colbuf[0][x] = p0; colbuf[1][x] = p1; colbuf[2][x] = p2;
            __syncthreads();
            if (x < P) {
                float q0 = -INFINITY, q1 = -INFINITY, q2 = -INFINITY;
                for (int c = x * kh; c < x * kh + kh; ++c) {
                    q0 = fmaxf(q0, colbuf[0][c]);
                    q1 = fmaxf(q1, colbuf[1][c]);
                    q2 = fmaxf(q2, colbuf[2][c]);
                }
                int idx = K_CUM[lvl] * NB + b * P * P + cr * P + x;
                atomicMax(&mws[idx],                 __float_as_uint(q0));
                atomicMax(&mws[idx + CELLS_TOT],     __float_as_uint(q1));
                atomicMax(&mws[idx + 2 * CELLS_TOT], __float_as_uint(q2));
            }
            __syncthreads();
        }
    }
}

// ---- K2: LDS-tiled bilinear levels 0..12, cached x-interpolated row pair ----
// src = ((2o+1)*P - 256)/512 : exact int; frac exact in fp32.
__global__ __launch_bounds__(256) void render_tiles(const float* __restrict__ tab,
                                                    const float* __restrict__ mws,
                                                    float* __restrict__ out)
{
    __shared__ float4 s[34 * 34];
    int blk   = blockIdx.x;
    int tile  = blk & 15;
    int plane = blk >> 4;            // 0..207
    int lvl   = plane >> 4;
    int b     = plane & 15;
    int P     = c_P[lvl];
    int yt0   = (tile >> 2) * 64;
    int xt0   = (tile & 3) * 64;

    int nlo  = ((2 * yt0 + 1) * P - 256) >> 9;
    int r_lo = nlo < 0 ? 0 : (nlo > P - 1 ? P - 1 : nlo);
    int nhi  = (((2 * (yt0 + 63) + 1) * P - 256) >> 9) + 1;
    int r_hi = nhi < 0 ? 0 : (nhi > P - 1 ? P - 1 : nhi);
    int mlo  = ((2 * xt0 + 1) * P - 256) >> 9;
    int c_lo = mlo < 0 ? 0 : (mlo > P - 1 ? P - 1 : mlo);
    int mhi  = (((2 * (xt0 + 63) + 1) * P - 256) >> 9) + 1;
    int c_hi = mhi < 0 ? 0 : (mhi > P - 1 ? P - 1 : mhi);
    int span_y = r_hi - r_lo + 1;
    int span_x = c_hi - c_lo + 1;

    // stage: read maxima, hash, gather table feature per window cell
    int planebase = c_CUM[lvl] * NB + b * P * P;
    const float* T = tab + (size_t)lvl * 196608;
    float gmul = c_G[lvl];
    int n = span_y * span_x;
    for (int t = threadIdx.x; t < n; t += 256) {
        int r = t / span_x, c = t - r * span_x;
        int idx = planebase + (r_lo + r) * P + c_lo + c;
        float m0 = mws[idx];
        float m1 = mws[idx + CELLS_TOT];
        float m2 = mws[idx + 2 * CELLS_TOT];
        uint32_t g = hash3(m0, m1, m2, gmul);
        float3 tv = *(const float3*)(T + g * 3);
        float4 fv; fv.x = tv.x; fv.y = tv.y; fv.z = tv.z; fv.w = 0.f;
        s[t] = fv;
    }
    __syncthreads();

    int lane = threadIdx.x & 63;
    int w    = threadIdx.x >> 6;
    int xq   = lane & 15;
    int rg   = lane >> 4;
    int xb   = xt0 + xq * 4;

    int ix0t[4], ix1t[4]; float wx0t[4], wx1t[4];
#pragma unroll
    for (int j = 0; j < 4; ++j) {
        int numx = (2 * (xb + j) + 1) * P - 256;
        int ix0  = numx >> 9;
        float fx = (float)(numx & 511) * (1.0f / 512.0f);
        int ix1;
        if (ix0 < 0)           { ix0 = 0;     ix1 = 0;     fx = 0.f; }
        else if (ix0 >= P - 1) { ix0 = P - 1; ix1 = P - 1; fx = 0.f; }
        else                   { ix1 = ix0 + 1; }
        ix0t[j] = ix0 - c_lo; ix1t[j] = ix1 - c_lo; wx1t[j] = fx; wx0t[j] = 1.f - fx;
    }

    // cached x-interpolated rows: r0v = row iy0, r1v = row iy1 (per channel x 4 px)
    int cur0 = -1, cur1 = -1;
    float r0v[3][4], r1v[3][4];

#pragma unroll
    for (int k = 0; k < 4; ++k) {
        int y = yt0 + w * 16 + rg * 4 + k;
        int numy = (2 * y + 1) * P - 256;
        int iy0  = numy >> 9;
        float fy = (float)(numy & 511) * (1.0f / 512.0f);
        int iy1;
        if (iy0 < 0)           { iy0 = 0;     iy1 = 0;     fy = 0.f; }
        else if (iy0 >= P - 1) { iy0 = P - 1; iy1 = P - 1; fy = 0.f; }
        else                   { iy1 = iy0 + 1; }

        if (iy0 != cur0) {
            if (iy0 == cur1) {
#pragma unroll
                for (int j = 0; j < 4; ++j) {
                    r0v[0][j] = r1v[0][j]; r0v[1][j] = r1v[1][j]; r0v[2][j] = r1v[2][j];
                }
            } else {
                const float4* p0 = s + (iy0 - r_lo) * span_x;
#pragma unroll
                for (int j = 0; j < 4; ++j) {
                    float4 a = p0[ix0t[j]], q = p0[ix1t[j]];
                    r0v[0][j] = wx0t[j] * a.x + wx1t[j] * q.x;
                    r0v[1][j] = wx0t[j] * a.y + wx1t[j] * q.y;
                    r0v[2][j] = wx0t[j] * a.z + wx1t[j] * q.z;
                }
            }
            cur0 = iy0;
        }
        if (iy1 != cur1) {
            if (iy1 == cur0 && iy1 == iy0) {   // clamped edge: row pair identical
#pragma unroll
                for (int j = 0; j < 4; ++j) {
                    r1v[0][j] = r0v[0][j]; r1v[1][j] = r0v[1][j]; r1v[2][j] = r0v[2][j];
                }
            } else {
                const float4* p1 = s + (iy1 - r_lo) * span_x;
#pragma unroll
                for (int j = 0; j < 4; ++j) {
                    float4 a = p1[ix0t[j]], q = p1[ix1t[j]];
                    r1v[0][j] = wx0t[j] * a.x + wx1t[j] * q.x;
                    r1v[1][j] = wx0t[j] * a.y + wx1t[j] * q.y;
                    r1v[2][j] = wx0t[j] * a.z + wx1t[j] * q.z;
                }
            }
            cur1 = iy1;
        }

        float wy1 = fy, wy0 = 1.f - fy;
        float* o = out + ((size_t)b * 48 + 3 * lvl) * 65536 + (size_t)y * 256 + xb;
#pragma unroll
        for (int c = 0; c < 3; ++c) {
            float4 q;
            q.x = wy0 * r0v[c][0] + wy1 * r1v[c][0];
            q.y = wy0 * r0v[c][1] + wy1 * r1v[c][1];
            q.z = wy0 * r0v[c][2] + wy1 * r1v[c][2];
            q.w = wy0 * r0v[c][3] + wy1 * r1v[c][3];
            *(float4*)(o + (size_t)c * 65536) = q;
        }
    }
}

extern "C" void kernel_launch(void* const* d_in, const int* in_sizes, int n_in,
                              void* d_out, int out_size, void* d_ws, size_t ws_size,
                              hipStream_t stream)
{
    const float* img = (const float*)d_in[0];   // (16,3,256,256) f32
    const float* tab = (const float*)d_in[1];   // (16,65536,3) f32
    float* out = (float*)d_out;                 // (16,48,256,256) f32
    float* mws = (float*)d_ws;                  // 1,600,992 f32 = 6.4 MB

    (void)hipMemsetAsync(mws, 0, (size_t)MWS_FLOATS * sizeof(float), stream);
    hipLaunchKernelGGL(pool_direct,  dim3(K1_BLOCKS), dim3(256), 0, stream, img, tab, (unsigned int*)mws, out);
    hipLaunchKernelGGL(render_tiles, dim3(TILE_BLOCKS), dim3(256), 0, stream, tab, mws, out);
}